// Round 2
// baseline (282.507 us; speedup 1.0000x reference)
//
#include <hip/hip_runtime.h>
#include <cstdint>
#include <cmath>

#define D_MODEL 1024
#define SEQ 2048
#define BATCH 4

typedef short bf16x8 __attribute__((ext_vector_type(8)));
typedef float f32x4 __attribute__((ext_vector_type(4)));

__device__ __forceinline__ short f2bf(float f) {
  union { float f; unsigned int u; } v; v.f = f;
  unsigned int r = (v.u + 0x7FFFu + ((v.u >> 16) & 1u)) >> 16;
  return (short)r;
}

__device__ __forceinline__ float bf2f(short h) {
  union { unsigned int u; float f; } v;
  v.u = ((unsigned int)(unsigned short)h) << 16;
  return v.f;
}

__device__ __forceinline__ f32x4 mfma16(bf16x8 a, bf16x8 b, f32x4 c) {
  return __builtin_amdgcn_mfma_f32_16x16x32_bf16(a, b, c, 0, 0, 0);
}

__device__ __forceinline__ void load_lds16(const void* g, void* l) {
  __builtin_amdgcn_global_load_lds(
      (const __attribute__((address_space(1))) unsigned int*)g,
      (__attribute__((address_space(3))) unsigned int*)l, 16, 0, 0);
}

// ---------------- prep: x fp32 -> bf16 ----------------
__global__ __launch_bounds__(256) void convert_x(const float* __restrict__ x,
                                                 short* __restrict__ xb) {
  int i = blockIdx.x * 256 + threadIdx.x;
  float4 f = ((const float4*)x)[i];
  short4 h;
  h.x = f2bf(f.x); h.y = f2bf(f.y); h.z = f2bf(f.z); h.w = f2bf(f.w);
  ((short4*)xb)[i] = h;
}

// ---------------- prep: W [k][n] fp32 -> Wt [n][k] bf16 ----------------
__global__ __launch_bounds__(256) void transpose_w(const float* __restrict__ Wq,
                                                   const float* __restrict__ Wk,
                                                   const float* __restrict__ Wv,
                                                   short* __restrict__ wt) {
  const int mat = blockIdx.z;
  const float* __restrict__ W = (mat == 0) ? Wq : (mat == 1) ? Wk : Wv;
  short* __restrict__ o = wt + (size_t)mat * (D_MODEL * D_MODEL);
  __shared__ float tile[32][33];
  const int k0 = blockIdx.x * 32, n0 = blockIdx.y * 32;
  const int lx = threadIdx.x & 31, ly = threadIdx.x >> 5;
#pragma unroll
  for (int i = 0; i < 4; ++i) {
    int r = ly + i * 8;
    tile[r][lx] = W[(size_t)(k0 + r) * D_MODEL + n0 + lx];
  }
  __syncthreads();
#pragma unroll
  for (int i = 0; i < 4; ++i) {
    int r = ly + i * 8;
    o[(size_t)(n0 + r) * D_MODEL + k0 + lx] = f2bf(tile[lx][r]);
  }
}

// ------- QKV GEMM: combined M=8192, N=3072, K=1024 -------
// 256x256 tile, BK=64, 512 thr (8 waves, 2Mx4N). Faithful m201 8-phase:
// per phase {ds_read quadrant | 1 half-tile stage (2 loads) | barrier |
// lgkmcnt(0)+sched_barrier | setprio(1) 16 MFMA setprio(0) | barrier},
// counted vmcnt(2) once per K-tile (never 0 in steady state).
// LDS chunk layout: pos p of row r holds global 16B chunk p ^ (r&7).
__global__ __launch_bounds__(512, 2) void qkv_gemm(
    const short* __restrict__ xb, const short* __restrict__ wt,
    const float* __restrict__ bq, const float* __restrict__ bk,
    const float* __restrict__ bv, short* __restrict__ qo,
    short* __restrict__ ko, short* __restrict__ vo) {
  const int m0 = blockIdx.x * 256;
  const int n0 = blockIdx.y * 256;   // global over 3072 (Wq|Wk|Wv rows)

  __shared__ short a_lds[2][256 * 64];  // 64 KB
  __shared__ short b_lds[2][256 * 64];  // 64 KB

  const int tid = threadIdx.x;
  const int wid = tid >> 6;        // 0..7
  const int lane = tid & 63;
  const int quad = lane >> 4;
  const int l16 = lane & 15;
  const int wr = wid >> 2;         // 0..1 -> wave m-offset wr*128
  const int wc = wid & 3;          // 0..3 -> wave n-offset wc*64
  const int sw8 = l16 & 7;
  const int p0 = (quad ^ sw8) * 16;        // byte off of ksub0 chunk
  const int p1 = ((4 + quad) ^ sw8) * 16;  // byte off of ksub1 chunk
  const int aro = (wr * 128 + l16) * 128;  // byte row base (A, frag i=0)
  const int bro = (wc * 64 + l16) * 128;   // byte row base (B, frag j=0)

  f32x4 acc[8][4] = {};

  // stage one half-tile (16 KB = 2 loads/thread) of tile t.
  // mh: 0=A rows 0-127, 1=A rows 128-255, 2=B rows 0-127, 3=B rows 128-255.
  // global src pre-swizzled so linear LDS dest + swizzled read match.
  auto stage_half = [&](int t, int mh) {
    const int buf = t & 1;
    const int k0 = t << 6;
    const short* __restrict__ src = (mh < 2) ? xb : wt;
    const int mb = (mh < 2) ? m0 : n0;
    char* base = (mh < 2) ? ((char*)a_lds + buf * 32768)
                          : ((char*)b_lds + buf * 32768);
    const int h = mh & 1;
#pragma unroll
    for (int l = 0; l < 2; ++l) {
      const int c = (l << 9) + tid;            // 0..1023
      const int row = (h << 7) + (c >> 3);     // 0..255
      const int g = (c & 7) ^ (row & 7);
      load_lds16(src + (size_t)(mb + row) * D_MODEL + k0 + (g << 3),
                 base + (size_t)row * 128 + ((c & 7) << 4));
    }
  };

  // ---- prologue: T0 fully + T1 half0; counted wait; raw barrier ----
  stage_half(0, 0); stage_half(0, 1); stage_half(0, 2); stage_half(0, 3);
  stage_half(1, 0);
  asm volatile("s_waitcnt vmcnt(2)" ::: "memory");   // T0 landed
  __builtin_amdgcn_s_barrier();

  for (int kt = 0; kt < 16; ++kt) {
    const int buf = kt & 1;
    const char* al = (const char*)a_lds + buf * 32768;
    const char* bl = (const char*)b_lds + buf * 32768;
    bf16x8 af[4][2], bfr[4][2];

    // ---- q0: read A0 (i0-3) + B0 (j0-1); stage (kt+1, A h1); MFMA Q00
#pragma unroll
    for (int i = 0; i < 4; ++i) {
      af[i][0] = *(const bf16x8*)(al + aro + i * 2048 + p0);
      af[i][1] = *(const bf16x8*)(al + aro + i * 2048 + p1);
    }
#pragma unroll
    for (int j = 0; j < 2; ++j) {
      bfr[j][0] = *(const bf16x8*)(bl + bro + j * 2048 + p0);
      bfr[j][1] = *(const bf16x8*)(bl + bro + j * 2048 + p1);
    }
    if (kt + 1 < 16) stage_half(kt + 1, 1);
    __builtin_amdgcn_s_barrier();
    asm volatile("s_waitcnt lgkmcnt(0)" ::: "memory");
    __builtin_amdgcn_sched_barrier(0);
    __builtin_amdgcn_s_setprio(1);
#pragma unroll
    for (int i = 0; i < 4; ++i)
#pragma unroll
      for (int j = 0; j < 2; ++j) {
        acc[i][j] = mfma16(af[i][0], bfr[j][0], acc[i][j]);
        acc[i][j] = mfma16(af[i][1], bfr[j][1], acc[i][j]);
      }
    __builtin_amdgcn_s_setprio(0);
    __builtin_amdgcn_s_barrier();

    // ---- q1: read B1 (j2-3); stage (kt+1, B h0); MFMA Q01 (i0-3 x j2-3)
#pragma unroll
    for (int j = 2; j < 4; ++j) {
      bfr[j][0] = *(const bf16x8*)(bl + bro + j * 2048 + p0);
      bfr[j][1] = *(const bf16x8*)(bl + bro + j * 2048 + p1);
    }
    if (kt + 1 < 16) stage_half(kt + 1, 2);
    __builtin_amdgcn_s_barrier();
    asm volatile("s_waitcnt lgkmcnt(0)" ::: "memory");
    __builtin_amdgcn_sched_barrier(0);
    __builtin_amdgcn_s_setprio(1);
#pragma unroll
    for (int i = 0; i < 4; ++i)
#pragma unroll
      for (int j = 2; j < 4; ++j) {
        acc[i][j] = mfma16(af[i][0], bfr[j][0], acc[i][j]);
        acc[i][j] = mfma16(af[i][1], bfr[j][1], acc[i][j]);
      }
    __builtin_amdgcn_s_setprio(0);
    __builtin_amdgcn_s_barrier();

    // ---- q2: read A1 (i4-7, reuse af regs); stage (kt+1, B h1); MFMA Q11
#pragma unroll
    for (int i = 0; i < 4; ++i) {
      af[i][0] = *(const bf16x8*)(al + aro + (i + 4) * 2048 + p0);
      af[i][1] = *(const bf16x8*)(al + aro + (i + 4) * 2048 + p1);
    }
    if (kt + 1 < 16) stage_half(kt + 1, 3);
    __builtin_amdgcn_s_barrier();
    asm volatile("s_waitcnt lgkmcnt(0)" ::: "memory");
    __builtin_amdgcn_sched_barrier(0);
    __builtin_amdgcn_s_setprio(1);
#pragma unroll
    for (int i = 0; i < 4; ++i)
#pragma unroll
      for (int j = 2; j < 4; ++j) {
        acc[i + 4][j] = mfma16(af[i][0], bfr[j][0], acc[i + 4][j]);
        acc[i + 4][j] = mfma16(af[i][1], bfr[j][1], acc[i + 4][j]);
      }
    __builtin_amdgcn_s_setprio(0);
    __builtin_amdgcn_s_barrier();   // all waves done reading buf

    // ---- q3: no ds_read; stage (kt+2, A h0) into freed buf; MFMA Q10;
    //      counted vmcnt (next tile's 4 halves landed), barrier.
    if (kt + 2 < 16) stage_half(kt + 2, 0);
    __builtin_amdgcn_s_barrier();
    __builtin_amdgcn_s_setprio(1);
#pragma unroll
    for (int i = 0; i < 4; ++i)
#pragma unroll
      for (int j = 0; j < 2; ++j) {
        acc[i + 4][j] = mfma16(af[i][0], bfr[j][0], acc[i + 4][j]);
        acc[i + 4][j] = mfma16(af[i][1], bfr[j][1], acc[i + 4][j]);
      }
    __builtin_amdgcn_s_setprio(0);
    if (kt + 1 < 16) {
      if (kt + 2 < 16)
        asm volatile("s_waitcnt vmcnt(2)" ::: "memory");
      else
        asm volatile("s_waitcnt vmcnt(0)" ::: "memory");
    }
    __builtin_amdgcn_s_barrier();
  }

  // epilogue: bias + bf16 store; block spans exactly one of Q/K/V.
  const int mat = n0 >> 10;
  const float* __restrict__ bias = (mat == 0) ? bq : (mat == 1) ? bk : bv;
  short* __restrict__ qko = (mat == 0) ? qo : ko;
  const int nbase = (n0 & 1023) + wc * 64;
#pragma unroll
  for (int i = 0; i < 8; ++i) {
#pragma unroll
    for (int j = 0; j < 4; ++j) {
#pragma unroll
      for (int r = 0; r < 4; ++r) {
        const int mrow = m0 + wr * 128 + i * 16 + quad * 4 + r;
        const int ncol = nbase + j * 16 + l16;
        const float val = acc[i][j][r] + bias[ncol];
        const short h = f2bf(val);
        if (mat == 2) {
          vo[((size_t)(mrow >> 11) * D_MODEL + ncol) * SEQ + (mrow & 2047)] = h;
        } else {
          qko[(size_t)mrow * D_MODEL + ncol] = h;
        }
      }
    }
  }
}

// ---------------- S = scale * Q K^T, causal tiles, dbuf + swizzle ----------------
__global__ __launch_bounds__(256) void sgemm(const short* __restrict__ qb,
                                             const short* __restrict__ kb,
                                             short* __restrict__ S) {
  if (blockIdx.y > blockIdx.x) return;
  const int m0 = blockIdx.x * 128;
  const int n0 = blockIdx.y * 128;
  const int b = blockIdx.z;
  const short* __restrict__ qp = qb + (size_t)b * SEQ * D_MODEL;
  const short* __restrict__ kp = kb + (size_t)b * SEQ * D_MODEL;

  __shared__ short a_lds[2][128 * 64];
  __shared__ short b_lds[2][128 * 64];

  const int tid = threadIdx.x;
  const int wid = tid >> 6;
  const int lane = tid & 63;
  const int quad = lane >> 4;
  const int l16 = lane & 15;
  const int mw = (wid >> 1) * 64;
  const int nw = (wid & 1) * 64;
  const int sw = l16 & 7;
  const int r_local = wid * 8 + (lane >> 3);
  const int c_sw = ((lane & 7) ^ (lane >> 3)) * 8;

  f32x4 acc[4][4] = {};

  auto stage = [&](int k0, int buf) {
#pragma unroll
    for (int it = 0; it < 4; ++it) {
      load_lds16(qp + (size_t)(m0 + it * 32 + r_local) * D_MODEL + k0 + c_sw,
                 (char*)a_lds[buf] + it * 4096 + wid * 1024);
      load_lds16(kp + (size_t)(n0 + it * 32 + r_local) * D_MODEL + k0 + c_sw,
                 (char*)b_lds[buf] + it * 4096 + wid * 1024);
    }
  };

  stage(0, 0);
  for (int k0 = 0; k0 < D_MODEL; k0 += 64) {
    const int buf = (k0 >> 6) & 1;
    __syncthreads();
    if (k0 + 64 < D_MODEL) stage(k0 + 64, buf ^ 1);
    const short* al = a_lds[buf];
    const short* bl = b_lds[buf];
#pragma unroll
    for (int kt = 0; kt < 2; ++kt) {
      bf16x8 af[4], bfr[4];
#pragma unroll
      for (int i = 0; i < 4; ++i)
        af[i] = *(const bf16x8*)(al + (mw + i * 16 + l16) * 64 +
                                 ((kt * 4 + quad) ^ sw) * 8);
#pragma unroll
      for (int i = 0; i < 4; ++i)
        bfr[i] = *(const bf16x8*)(bl + (nw + i * 16 + l16) * 64 +
                                  ((kt * 4 + quad) ^ sw) * 8);
#pragma unroll
      for (int i = 0; i < 4; ++i)
#pragma unroll
        for (int j = 0; j < 4; ++j)
          acc[i][j] = mfma16(af[i], bfr[j], acc[i][j]);
    }
  }
#pragma unroll
  for (int i = 0; i < 4; ++i) {
#pragma unroll
    for (int j = 0; j < 4; ++j) {
#pragma unroll
      for (int r = 0; r < 4; ++r) {
        const int mrow = m0 + mw + i * 16 + quad * 4 + r;
        const int ncol = n0 + nw + j * 16 + l16;
        S[((size_t)b * SEQ + mrow) * SEQ + ncol] = f2bf(acc[i][j][r] * 0.03125f);
      }
    }
  }
}

// ---------------- row softmax: S bf16 -> P bf16 (normalized, zero-padded) --------
__global__ __launch_bounds__(256) void softmax_rows(const short* __restrict__ S,
                                                    short* __restrict__ P) {
  const int row = blockIdx.x;          // 0..8191
  const int t = row & (SEQ - 1);
  const int tid = threadIdx.x;
  const short* __restrict__ srow = S + (size_t)row * SEQ;
  short* __restrict__ prow = P + (size_t)row * SEQ;

  __shared__ float red[4];

  float v[8];
#pragma unroll
  for (int i = 0; i < 8; ++i) {
    const int c = tid + i * 256;
    v[i] = (c <= t) ? bf2f(srow[c]) : -1e30f;
  }
  float m = v[0];
#pragma unroll
  for (int i = 1; i < 8; ++i) m = fmaxf(m, v[i]);
#pragma unroll
  for (int o = 32; o; o >>= 1) m = fmaxf(m, __shfl_xor(m, o));
  if ((tid & 63) == 0) red[tid >> 6] = m;
  __syncthreads();
  m = fmaxf(fmaxf(red[0], red[1]), fmaxf(red[2], red[3]));

  float e[8];
  float s = 0.f;
#pragma unroll
  for (int i = 0; i < 8; ++i) {
    e[i] = __expf(v[i] - m);   // -1e30 - m underflows to 0
    s += e[i];
  }
#pragma unroll
  for (int o = 32; o; o >>= 1) s += __shfl_xor(s, o);
  __syncthreads();
  if ((tid & 63) == 0) red[tid >> 6] = s;
  __syncthreads();
  s = red[0] + red[1] + red[2] + red[3];
  const float rinv = 1.0f / s;
  const int nwr = (t >> 8) + 1;   // chunks to write: covers pvgemm read extent
#pragma unroll
  for (int i = 0; i < 8; ++i)
    if (i < nwr) prow[tid + i * 256] = f2bf(e[i] * rinv);
}

// ---------------- O = P V (B = V^T layout), causal K, dbuf + swizzle -------------
// grid (8,4,16): x=d tile, y=batch, z: m0=(15-z)*128 (LPT: longest-K first).
__global__ __launch_bounds__(256) void pvgemm(const short* __restrict__ P,
                                              const short* __restrict__ vtb,
                                              float* __restrict__ out) {
  const int n0 = blockIdx.x * 128;
  const int b = blockIdx.y;
  const int m0 = (15 - blockIdx.z) * 128;
  const short* __restrict__ pp = P + (size_t)b * SEQ * SEQ;
  const short* __restrict__ vp = vtb + (size_t)b * D_MODEL * SEQ;
  const int kmax = m0 + 128;

  __shared__ short a_lds[2][128 * 64];
  __shared__ short b_lds[2][128 * 64];

  const int tid = threadIdx.x;
  const int wid = tid >> 6;
  const int lane = tid & 63;
  const int quad = lane >> 4;
  const int l16 = lane & 15;
  const int mw = (wid >> 1) * 64;
  const int nw = (wid & 1) * 64;
  const int sw = l16 & 7;
  const int r_local = wid * 8 + (lane >> 3);
  const int c_sw = ((lane & 7) ^ (lane >> 3)) * 8;

  f32x4 acc[4][4] = {};

  auto stage = [&](int k0, int buf) {
#pragma unroll
    for (int it = 0; it < 4; ++it) {
      load_lds16(pp + (size_t)(m0 + it * 32 + r_local) * SEQ + k0 + c_sw,
                 (char*)a_lds[buf] + it * 4096 + wid * 1024);
      load_lds16(vp + (size_t)(n0 + it * 32 + r_local) * SEQ + k0 + c_sw,
                 (char*)b_lds[buf] + it * 4096 + wid * 1024);
    }
  };

  stage(0, 0);
  for (int k0 = 0; k0 < kmax; k0 += 64) {
    const int buf = (k0 >> 6) & 1;
    __syncthreads();
    if (k0 + 64 < kmax) stage(k0 + 64, buf ^ 1);
    const short* al = a_lds[buf];
    const short* bl = b_lds[buf];
#pragma unroll
    for (int kt = 0; kt < 2; ++kt) {
      bf16x8 af[4], bfr[4];
#pragma unroll
      for (int i = 0; i < 4; ++i)
        af[i] = *(const bf16x8*)(al + (mw + i * 16 + l16) * 64 +
                                 ((kt * 4 + quad) ^ sw) * 8);
#pragma unroll
      for (int i = 0; i < 4; ++i)
        bfr[i] = *(const bf16x8*)(bl + (nw + i * 16 + l16) * 64 +
                                  ((kt * 4 + quad) ^ sw) * 8);
#pragma unroll
      for (int i = 0; i < 4; ++i)
#pragma unroll
        for (int j = 0; j < 4; ++j)
          acc[i][j] = mfma16(af[i], bfr[j], acc[i][j]);
    }
  }
#pragma unroll
  for (int i = 0; i < 4; ++i) {
#pragma unroll
    for (int j = 0; j < 4; ++j) {
#pragma unroll
      for (int r = 0; r < 4; ++r) {
        const int mrow = m0 + mw + i * 16 + quad * 4 + r;
        const int ncol = n0 + nw + j * 16 + l16;
        out[((size_t)b * SEQ + mrow) * D_MODEL + ncol] = acc[i][j][r];
      }
    }
  }
}

extern "C" void kernel_launch(void* const* d_in, const int* in_sizes, int n_in,
                              void* d_out, int out_size, void* d_ws, size_t ws_size,
                              hipStream_t stream) {
  (void)in_sizes; (void)n_in; (void)out_size; (void)ws_size;
  const float* x  = (const float*)d_in[0];
  const float* Wq = (const float*)d_in[1];
  const float* bq = (const float*)d_in[2];
  const float* Wk = (const float*)d_in[3];
  const float* bk = (const float*)d_in[4];
  const float* Wv = (const float*)d_in[5];
  const float* bv = (const float*)d_in[6];
  float* out = (float*)d_out;

  char* ws = (char*)d_ws;
  short* xb = (short*)(ws);                 // 16 MB   [dead after qkv_gemm]
  short* wt = (short*)(ws + 16777216);      // 6 MB    [dead after qkv_gemm]
  short* qo = (short*)(ws + 23068672);      // 16 MB   [dead after sgemm]
  short* ko = (short*)(ws + 39845888);      // 16 MB   [dead after sgemm]
  short* vo = (short*)(ws + 56623104);      // 16 MB   transposed [b][d][s]
  short* S  = (short*)(ws + 73400320);      // 32 MB bf16 [b][t][s]
  short* P  = (short*)(ws);                 // 32 MB, aliases xb/wt/qo (dead by then)

  convert_x<<<dim3(8192), dim3(256), 0, stream>>>(x, xb);
  transpose_w<<<dim3(32, 32, 3), dim3(256), 0, stream>>>(Wq, Wk, Wv, wt);
  qkv_gemm<<<dim3(32, 12), dim3(512), 0, stream>>>(xb, wt, bq, bk, bv, qo, ko, vo);
  sgemm<<<dim3(16, 16, BATCH), dim3(256), 0, stream>>>(qo, ko, S);
  softmax_rows<<<dim3(BATCH * SEQ), dim3(256), 0, stream>>>(S, P);
  pvgemm<<<dim3(8, BATCH, 16), dim3(256), 0, stream>>>(P, vo, out);
}

// Round 3
// 258.052 us; speedup vs baseline: 1.0948x; 1.0948x over previous
//
#include <hip/hip_runtime.h>
#include <cstdint>
#include <cmath>

#define D_MODEL 1024
#define SEQ 2048
#define BATCH 4

typedef short bf16x8 __attribute__((ext_vector_type(8)));
typedef float f32x4 __attribute__((ext_vector_type(4)));

__device__ __forceinline__ short f2bf(float f) {
  union { float f; unsigned int u; } v; v.f = f;
  unsigned int r = (v.u + 0x7FFFu + ((v.u >> 16) & 1u)) >> 16;
  return (short)r;
}

__device__ __forceinline__ float bf2f(short h) {
  union { unsigned int u; float f; } v;
  v.u = ((unsigned int)(unsigned short)h) << 16;
  return v.f;
}

__device__ __forceinline__ f32x4 mfma16(bf16x8 a, bf16x8 b, f32x4 c) {
  return __builtin_amdgcn_mfma_f32_16x16x32_bf16(a, b, c, 0, 0, 0);
}

__device__ __forceinline__ void load_lds16(const void* g, void* l) {
  __builtin_amdgcn_global_load_lds(
      (const __attribute__((address_space(1))) unsigned int*)g,
      (__attribute__((address_space(3))) unsigned int*)l, 16, 0, 0);
}

// ---------------- prep: x fp32 -> bf16 ----------------
__global__ __launch_bounds__(256) void convert_x(const float* __restrict__ x,
                                                 short* __restrict__ xb) {
  int i = blockIdx.x * 256 + threadIdx.x;
  float4 f = ((const float4*)x)[i];
  short4 h;
  h.x = f2bf(f.x); h.y = f2bf(f.y); h.z = f2bf(f.z); h.w = f2bf(f.w);
  ((short4*)xb)[i] = h;
}

// ---------------- prep: W [k][n] fp32 -> Wt [n][k] bf16 ----------------
__global__ __launch_bounds__(256) void transpose_w(const float* __restrict__ Wq,
                                                   const float* __restrict__ Wk,
                                                   const float* __restrict__ Wv,
                                                   short* __restrict__ wt) {
  const int mat = blockIdx.z;
  const float* __restrict__ W = (mat == 0) ? Wq : (mat == 1) ? Wk : Wv;
  short* __restrict__ o = wt + (size_t)mat * (D_MODEL * D_MODEL);
  __shared__ float tile[32][33];
  const int k0 = blockIdx.x * 32, n0 = blockIdx.y * 32;
  const int lx = threadIdx.x & 31, ly = threadIdx.x >> 5;
#pragma unroll
  for (int i = 0; i < 4; ++i) {
    int r = ly + i * 8;
    tile[r][lx] = W[(size_t)(k0 + r) * D_MODEL + n0 + lx];
  }
  __syncthreads();
#pragma unroll
  for (int i = 0; i < 4; ++i) {
    int r = ly + i * 8;
    o[(size_t)(n0 + r) * D_MODEL + k0 + lx] = f2bf(tile[lx][r]);
  }
}

// ------- QKV GEMM: 256x128 tile, 512 thr, BK=32, dbuf (48 KB -> 3 WGs/CU) -------
// C[m][n] = sum_k xb[m][k] * Wt[n][k] + bias[n]
// LDS chunk pos p of row r holds global 8-elem chunk p ^ ((r>>1)&3).
__global__ __launch_bounds__(512, 4) void qkv_gemm(
    const short* __restrict__ xb, const short* __restrict__ wt,
    const float* __restrict__ bq, const float* __restrict__ bk,
    const float* __restrict__ bv, short* __restrict__ qo,
    short* __restrict__ ko, short* __restrict__ vo) {
  const int m0 = blockIdx.x * 256;
  const int n0 = blockIdx.y * 128;
  const int mat = blockIdx.z;
  const short* __restrict__ w = wt + (size_t)mat * (D_MODEL * D_MODEL);
  const float* __restrict__ bias = (mat == 0) ? bq : (mat == 1) ? bk : bv;

  __shared__ short a_lds[2][256 * 32];  // 2 x 16 KB
  __shared__ short b_lds[2][128 * 32];  // 2 x 8 KB

  const int tid = threadIdx.x;
  const int wid = tid >> 6;        // 0..7
  const int lane = tid & 63;
  const int quad = lane >> 4;
  const int l16 = lane & 15;
  const int wm = (wid >> 1) * 64;
  const int wn = (wid & 1) * 64;
  const int key = (l16 >> 1) & 3;  // read-side swizzle key (2-way max conflict)

  f32x4 acc[4][4] = {};

  auto stage = [&](int k0, int buf) {
    // A: 1024 16B-chunks, 2 per thread; chunk c -> row c>>2, lds pos c&3,
    // global chunk (c&3)^((c>>3)&3)
#pragma unroll
    for (int h = 0; h < 2; ++h) {
      const int c = tid + h * 512;
      load_lds16(xb + (size_t)(m0 + (c >> 2)) * D_MODEL + k0 +
                     (((c & 3) ^ ((c >> 3) & 3)) << 3),
                 (char*)&a_lds[buf][c * 8]);
    }
    // B: 512 chunks, 1 per thread
    load_lds16(w + (size_t)(n0 + (tid >> 2)) * D_MODEL + k0 +
                   (((tid & 3) ^ ((tid >> 3) & 3)) << 3),
               (char*)&b_lds[buf][tid * 8]);
  };

  stage(0, 0);
  for (int k0 = 0; k0 < D_MODEL; k0 += 32) {
    const int buf = (k0 >> 5) & 1;
    __syncthreads();
    if (k0 + 32 < D_MODEL) stage(k0 + 32, buf ^ 1);
    const short* al = a_lds[buf];
    const short* bl = b_lds[buf];
    bf16x8 af[4], bfr[4];
#pragma unroll
    for (int i = 0; i < 4; ++i)
      af[i] = *(const bf16x8*)(al + (wm + i * 16 + l16) * 32 +
                               ((quad ^ key) << 3));
#pragma unroll
    for (int j = 0; j < 4; ++j)
      bfr[j] = *(const bf16x8*)(bl + (wn + j * 16 + l16) * 32 +
                                ((quad ^ key) << 3));
#pragma unroll
    for (int i = 0; i < 4; ++i)
#pragma unroll
      for (int j = 0; j < 4; ++j)
        acc[i][j] = mfma16(af[i], bfr[j], acc[i][j]);
  }
#pragma unroll
  for (int i = 0; i < 4; ++i) {
#pragma unroll
    for (int j = 0; j < 4; ++j) {
#pragma unroll
      for (int r = 0; r < 4; ++r) {
        const int mrow = m0 + wm + i * 16 + quad * 4 + r;
        const int ncol = n0 + wn + j * 16 + l16;
        const float val = acc[i][j][r] + bias[ncol];
        const short h = f2bf(val);
        if (mat == 2) {
          const int bb = mrow >> 11;
          const int t = mrow & 2047;
          vo[((size_t)bb * D_MODEL + ncol) * SEQ + t] = h;
        } else if (mat == 0) {
          qo[(size_t)mrow * D_MODEL + ncol] = h;
        } else {
          ko[(size_t)mrow * D_MODEL + ncol] = h;
        }
      }
    }
  }
}

// ------- S = scale * Q K^T: 256x128 tile, 512 thr, BK=32, dbuf (48 KB) -------
// Same proven structure as qkv_gemm. Causal: keep n-tile x iff x <= 2y+1.
// grid (16, 8, 4): x = n-tile, y = m-tile, z = batch.
__global__ __launch_bounds__(512, 4) void sgemm(const short* __restrict__ qb,
                                                const short* __restrict__ kb,
                                                short* __restrict__ S) {
  if ((blockIdx.x >> 1) > blockIdx.y) return;   // fully above diagonal
  const int n0 = blockIdx.x * 128;
  const int m0 = blockIdx.y * 256;
  const int b = blockIdx.z;
  const short* __restrict__ qp = qb + (size_t)b * SEQ * D_MODEL;
  const short* __restrict__ kp = kb + (size_t)b * SEQ * D_MODEL;

  __shared__ short a_lds[2][256 * 32];  // 2 x 16 KB
  __shared__ short b_lds[2][128 * 32];  // 2 x 8 KB

  const int tid = threadIdx.x;
  const int wid = tid >> 6;
  const int lane = tid & 63;
  const int quad = lane >> 4;
  const int l16 = lane & 15;
  const int wm = (wid >> 1) * 64;
  const int wn = (wid & 1) * 64;
  const int key = (l16 >> 1) & 3;

  f32x4 acc[4][4] = {};

  auto stage = [&](int k0, int buf) {
#pragma unroll
    for (int h = 0; h < 2; ++h) {
      const int c = tid + h * 512;
      load_lds16(qp + (size_t)(m0 + (c >> 2)) * D_MODEL + k0 +
                     (((c & 3) ^ ((c >> 3) & 3)) << 3),
                 (char*)&a_lds[buf][c * 8]);
    }
    load_lds16(kp + (size_t)(n0 + (tid >> 2)) * D_MODEL + k0 +
                   (((tid & 3) ^ ((tid >> 3) & 3)) << 3),
               (char*)&b_lds[buf][tid * 8]);
  };

  stage(0, 0);
  for (int k0 = 0; k0 < D_MODEL; k0 += 32) {
    const int buf = (k0 >> 5) & 1;
    __syncthreads();
    if (k0 + 32 < D_MODEL) stage(k0 + 32, buf ^ 1);
    const short* al = a_lds[buf];
    const short* bl = b_lds[buf];
    bf16x8 af[4], bfr[4];
#pragma unroll
    for (int i = 0; i < 4; ++i)
      af[i] = *(const bf16x8*)(al + (wm + i * 16 + l16) * 32 +
                               ((quad ^ key) << 3));
#pragma unroll
    for (int j = 0; j < 4; ++j)
      bfr[j] = *(const bf16x8*)(bl + (wn + j * 16 + l16) * 32 +
                                ((quad ^ key) << 3));
#pragma unroll
    for (int i = 0; i < 4; ++i)
#pragma unroll
      for (int j = 0; j < 4; ++j)
        acc[i][j] = mfma16(af[i], bfr[j], acc[i][j]);
  }
#pragma unroll
  for (int i = 0; i < 4; ++i) {
#pragma unroll
    for (int j = 0; j < 4; ++j) {
#pragma unroll
      for (int r = 0; r < 4; ++r) {
        const int mrow = m0 + wm + i * 16 + quad * 4 + r;
        const int ncol = n0 + wn + j * 16 + l16;
        S[((size_t)b * SEQ + mrow) * SEQ + ncol] = f2bf(acc[i][j][r] * 0.03125f);
      }
    }
  }
}

// ---------------- row softmax: S bf16 -> P bf16 (normalized, zero-padded) --------
__global__ __launch_bounds__(256) void softmax_rows(const short* __restrict__ S,
                                                    short* __restrict__ P) {
  const int row = blockIdx.x;          // 0..8191
  const int t = row & (SEQ - 1);
  const int tid = threadIdx.x;
  const short* __restrict__ srow = S + (size_t)row * SEQ;
  short* __restrict__ prow = P + (size_t)row * SEQ;

  __shared__ float red[4];

  const int nrd = (t >> 8) + 1;  // chunks with any valid (written) cols
  float v[8];
#pragma unroll
  for (int i = 0; i < 8; ++i) {
    const int c = tid + i * 256;
    // chunks >= nrd are fully masked AND unwritten by causal sgemm: skip load
    v[i] = (i < nrd) ? ((c <= t) ? bf2f(srow[c]) : -1e30f) : -1e30f;
  }
  float m = v[0];
#pragma unroll
  for (int i = 1; i < 8; ++i) m = fmaxf(m, v[i]);
#pragma unroll
  for (int o = 32; o; o >>= 1) m = fmaxf(m, __shfl_xor(m, o));
  if ((tid & 63) == 0) red[tid >> 6] = m;
  __syncthreads();
  m = fmaxf(fmaxf(red[0], red[1]), fmaxf(red[2], red[3]));

  float e[8];
  float s = 0.f;
#pragma unroll
  for (int i = 0; i < 8; ++i) {
    e[i] = __expf(v[i] - m);   // -1e30 - m underflows to 0
    s += e[i];
  }
#pragma unroll
  for (int o = 32; o; o >>= 1) s += __shfl_xor(s, o);
  __syncthreads();
  if ((tid & 63) == 0) red[tid >> 6] = s;
  __syncthreads();
  s = red[0] + red[1] + red[2] + red[3];
  const float rinv = 1.0f / s;
  const int nwr = nrd;   // chunks to write: covers pvgemm read extent
#pragma unroll
  for (int i = 0; i < 8; ++i)
    if (i < nwr) prow[tid + i * 256] = f2bf(e[i] * rinv);
}

// ---------------- O = P V (B = V^T layout), causal K, dbuf + swizzle -------------
// grid (8,4,16): x=d tile, y=batch, z: balanced K-pairing — blocks i and i+256
// land on the same CU (same x,y; z differs by 8); zp<8 -> K in {2048..1152}
// (long, dispatched first), zp>=8 -> K in {128..1024}; each pair sums K=2176.
__global__ __launch_bounds__(256) void pvgemm(const short* __restrict__ P,
                                              const short* __restrict__ vtb,
                                              float* __restrict__ out) {
  const int n0 = blockIdx.x * 128;
  const int b = blockIdx.y;
  const int zp = blockIdx.z;
  const int m0 = ((zp < 8) ? (15 - zp) : (zp - 8)) * 128;
  const short* __restrict__ pp = P + (size_t)b * SEQ * SEQ;
  const short* __restrict__ vp = vtb + (size_t)b * D_MODEL * SEQ;
  const int kmax = m0 + 128;

  __shared__ short a_lds[2][128 * 64];
  __shared__ short b_lds[2][128 * 64];

  const int tid = threadIdx.x;
  const int wid = tid >> 6;
  const int lane = tid & 63;
  const int quad = lane >> 4;
  const int l16 = lane & 15;
  const int mw = (wid >> 1) * 64;
  const int nw = (wid & 1) * 64;
  const int sw = l16 & 7;
  const int r_local = wid * 8 + (lane >> 3);
  const int c_sw = ((lane & 7) ^ (lane >> 3)) * 8;

  f32x4 acc[4][4] = {};

  auto stage = [&](int k0, int buf) {
#pragma unroll
    for (int it = 0; it < 4; ++it) {
      load_lds16(pp + (size_t)(m0 + it * 32 + r_local) * SEQ + k0 + c_sw,
                 (char*)a_lds[buf] + it * 4096 + wid * 1024);
      load_lds16(vp + (size_t)(n0 + it * 32 + r_local) * SEQ + k0 + c_sw,
                 (char*)b_lds[buf] + it * 4096 + wid * 1024);
    }
  };

  stage(0, 0);
  for (int k0 = 0; k0 < kmax; k0 += 64) {
    const int buf = (k0 >> 6) & 1;
    __syncthreads();
    if (k0 + 64 < kmax) stage(k0 + 64, buf ^ 1);
    const short* al = a_lds[buf];
    const short* bl = b_lds[buf];
#pragma unroll
    for (int kt = 0; kt < 2; ++kt) {
      bf16x8 af[4], bfr[4];
#pragma unroll
      for (int i = 0; i < 4; ++i)
        af[i] = *(const bf16x8*)(al + (mw + i * 16 + l16) * 64 +
                                 ((kt * 4 + quad) ^ sw) * 8);
#pragma unroll
      for (int i = 0; i < 4; ++i)
        bfr[i] = *(const bf16x8*)(bl + (nw + i * 16 + l16) * 64 +
                                  ((kt * 4 + quad) ^ sw) * 8);
#pragma unroll
      for (int i = 0; i < 4; ++i)
#pragma unroll
        for (int j = 0; j < 4; ++j)
          acc[i][j] = mfma16(af[i], bfr[j], acc[i][j]);
    }
  }
#pragma unroll
  for (int i = 0; i < 4; ++i) {
#pragma unroll
    for (int j = 0; j < 4; ++j) {
#pragma unroll
      for (int r = 0; r < 4; ++r) {
        const int mrow = m0 + mw + i * 16 + quad * 4 + r;
        const int ncol = n0 + nw + j * 16 + l16;
        out[((size_t)b * SEQ + mrow) * D_MODEL + ncol] = acc[i][j][r];
      }
    }
  }
}

extern "C" void kernel_launch(void* const* d_in, const int* in_sizes, int n_in,
                              void* d_out, int out_size, void* d_ws, size_t ws_size,
                              hipStream_t stream) {
  (void)in_sizes; (void)n_in; (void)out_size; (void)ws_size;
  const float* x  = (const float*)d_in[0];
  const float* Wq = (const float*)d_in[1];
  const float* bq = (const float*)d_in[2];
  const float* Wk = (const float*)d_in[3];
  const float* bk = (const float*)d_in[4];
  const float* Wv = (const float*)d_in[5];
  const float* bv = (const float*)d_in[6];
  float* out = (float*)d_out;

  char* ws = (char*)d_ws;
  short* xb = (short*)(ws);                 // 16 MB   [dead after qkv_gemm]
  short* wt = (short*)(ws + 16777216);      // 6 MB    [dead after qkv_gemm]
  short* qo = (short*)(ws + 23068672);      // 16 MB   [dead after sgemm]
  short* ko = (short*)(ws + 39845888);      // 16 MB   [dead after sgemm]
  short* vo = (short*)(ws + 56623104);      // 16 MB   transposed [b][d][s]
  short* S  = (short*)(ws + 73400320);      // 32 MB bf16 [b][t][s]
  short* P  = (short*)(ws);                 // 32 MB, aliases xb/wt/qo (dead by then)

  convert_x<<<dim3(8192), dim3(256), 0, stream>>>(x, xb);
  transpose_w<<<dim3(32, 32, 3), dim3(256), 0, stream>>>(Wq, Wk, Wv, wt);
  qkv_gemm<<<dim3(32, 8, 3), dim3(512), 0, stream>>>(xb, wt, bq, bk, bv, qo, ko, vo);
  sgemm<<<dim3(16, 8, BATCH), dim3(512), 0, stream>>>(qo, ko, S);
  softmax_rows<<<dim3(BATCH * SEQ), dim3(256), 0, stream>>>(S, P);
  pvgemm<<<dim3(8, BATCH, 16), dim3(256), 0, stream>>>(P, vo, out);
}